// Round 1
// baseline (299.544 us; speedup 1.0000x reference)
//
#include <hip/hip_runtime.h>
#include <stdint.h>

#define BATCH 4
#define SEQ   1024
#define NHEAD 16
#define DHEAD 128
#define HDIM  2048
#define GM    4096   /* BATCH*SEQ */
#define GN    2048
#define GK    2048

typedef __attribute__((ext_vector_type(8))) short short8;
typedef __attribute__((ext_vector_type(4))) float f32x4;

__device__ __forceinline__ uint16_t f2bf(float f) {
  uint32_t u = __builtin_bit_cast(uint32_t, f);
  u += 0x7fffu + ((u >> 16) & 1u);
  return (uint16_t)(u >> 16);
}
__device__ __forceinline__ float bf2f(uint16_t h) {
  return __builtin_bit_cast(float, (uint32_t)h << 16);
}

// XOR swizzles (involutions): spread 16B granules across bank quads.
// rowlen 64B: XOR addr bits 4-5 with row bits 1-2 (addr bits 7-8)
__device__ __forceinline__ uint32_t swz64(uint32_t a)  { return a ^ (((a >> 7) & 3u) << 4); }
// rowlen 128B: XOR addr bits 4-6 with row bits 0-2 (addr bits 7-9)
__device__ __forceinline__ uint32_t swz128(uint32_t a) { return a ^ (((a >> 7) & 7u) << 4); }
// rowlen 256B: XOR addr bits 4-6 with row bits 0-2 (addr bits 8-10)
__device__ __forceinline__ uint32_t swz256(uint32_t a) { return a ^ (((a >> 8) & 7u) << 4); }

#define GAS __attribute__((address_space(1)))
#define LAS __attribute__((address_space(3)))
__device__ __forceinline__ void gload_lds16(const void* g, void* l) {
  // dest = wave-uniform LDS base + lane*16 (HW); src is per-lane.
  __builtin_amdgcn_global_load_lds((GAS const void*)g, (LAS void*)l, 16, 0, 0);
}

// ---------------- fp32 -> bf16 convert (8 elems/thread) ----------------
__global__ void cvt_kernel(const float* __restrict__ in, uint16_t* __restrict__ out, int n8) {
  int i = blockIdx.x * 256 + threadIdx.x;
  if (i >= n8) return;
  const float4* p = (const float4*)in + (size_t)i * 2;
  float4 a = p[0], b = p[1];
  uint32_t w0 = f2bf(a.x) | ((uint32_t)f2bf(a.y) << 16);
  uint32_t w1 = f2bf(a.z) | ((uint32_t)f2bf(a.w) << 16);
  uint32_t w2 = f2bf(b.x) | ((uint32_t)f2bf(b.y) << 16);
  uint32_t w3 = f2bf(b.z) | ((uint32_t)f2bf(b.w) << 16);
  int4 r; r.x = (int)w0; r.y = (int)w1; r.z = (int)w2; r.w = (int)w3;
  *(int4*)(out + (size_t)i * 8) = r;
}

// ---------------- RoPE in-place on q/k (8 elems = 4 pairs /thread) ----------------
__global__ void rope_kernel(uint16_t* __restrict__ qb, uint16_t* __restrict__ kb,
                            const float* __restrict__ fcos, const float* __restrict__ fsin) {
  uint32_t i = blockIdx.x * 256 + threadIdx.x;       // 8-elem group, 1,048,576 total
  uint16_t* p = (blockIdx.y == 0 ? qb : kb) + (size_t)i * 8;
  uint32_t e0 = i * 8;
  uint32_t row = e0 >> 11;          // /HDIM
  uint32_t col = e0 & 2047;
  uint32_t s = row & (SEQ - 1);
  uint32_t pi = (col & (DHEAD - 1)) >> 1;            // pair idx, multiple of 4
  float4 cv = *(const float4*)(fcos + (size_t)s * 64 + pi);
  float4 sv = *(const float4*)(fsin + (size_t)s * 64 + pi);
  int4 raw = *(const int4*)p;
  uint16_t u[8]; *(int4*)u = raw;
  float cc[4] = {cv.x, cv.y, cv.z, cv.w}, ss[4] = {sv.x, sv.y, sv.z, sv.w};
#pragma unroll
  for (int t = 0; t < 4; ++t) {
    float x0 = bf2f(u[2 * t]), x1 = bf2f(u[2 * t + 1]);
    float o0 = x0 * cc[t] - x1 * ss[t];
    float o1 = x0 * ss[t] + x1 * cc[t];
    u[2 * t] = f2bf(o0); u[2 * t + 1] = f2bf(o1);
  }
  *(int4*)p = *(int4*)u;
}

// ---------------- GEMM: C = A(MxK) @ W(NxK)^T + bias ----------------
// 128x128 tile, BK=32, 4 waves 2x2, 16x16x32 bf16 MFMA, global_load_lds staging.
template <int OUTF32>
__device__ __forceinline__ void gemm_body(const uint16_t* __restrict__ A,
                                          const uint16_t* __restrict__ Bw,
                                          const float* __restrict__ bias,
                                          void* __restrict__ Cout) {
  __shared__ __align__(16) char smA[128 * 64];
  __shared__ __align__(16) char smB[128 * 64];
  const int tid = threadIdx.x, lane = tid & 63, wid = tid >> 6;
  const int c = lane & 15, g = lane >> 4;
  const int row0 = blockIdx.x * 128, col0 = blockIdx.y * 128;
  const int wr = wid >> 1, wc = wid & 1;
  f32x4 acc[4][4] = {};
  const uint32_t oBase = wid * 2048 + lane * 16;

  for (int kk = 0; kk < GK; kk += 32) {
#pragma unroll
    for (int q = 0; q < 2; ++q) {
      uint32_t o = oBase + q * 1024;
      uint32_t r = o >> 6;
      uint32_t cb = swz64(o) & 63;  // pre-swizzled source -> linear dest
      gload_lds16((const char*)A + ((size_t)(row0 + r) * GK + kk) * 2 + cb,
                  smA + wid * 2048 + q * 1024);
      gload_lds16((const char*)Bw + ((size_t)(col0 + r) * GK + kk) * 2 + cb,
                  smB + wid * 2048 + q * 1024);
    }
    __syncthreads();   // drains vmcnt(0): staged data visible
    short8 af[4], bf[4];
#pragma unroll
    for (int m = 0; m < 4; ++m)
      af[m] = *(const short8*)(smA + swz64((uint32_t)((wr * 64 + m * 16 + c) * 64 + g * 16)));
#pragma unroll
    for (int n = 0; n < 4; ++n)
      bf[n] = *(const short8*)(smB + swz64((uint32_t)((wc * 64 + n * 16 + c) * 64 + g * 16)));
#pragma unroll
    for (int m = 0; m < 4; ++m)
#pragma unroll
      for (int n = 0; n < 4; ++n)
        acc[m][n] = __builtin_amdgcn_mfma_f32_16x16x32_bf16(af[m], bf[n], acc[m][n], 0, 0, 0);
    __syncthreads();   // protect LDS before next stage
  }

  float bn[4];
#pragma unroll
  for (int n = 0; n < 4; ++n) bn[n] = bias[col0 + wc * 64 + n * 16 + c];
#pragma unroll
  for (int m = 0; m < 4; ++m) {
    const int gr = row0 + wr * 64 + m * 16 + g * 4;
#pragma unroll
    for (int n = 0; n < 4; ++n) {
      const int gc = col0 + wc * 64 + n * 16 + c;
#pragma unroll
      for (int jj = 0; jj < 4; ++jj) {
        float v = acc[m][n][jj] + bn[n];
        if (OUTF32)
          ((float*)Cout)[(size_t)(gr + jj) * GN + gc] = v;
        else
          ((uint16_t*)Cout)[(size_t)(gr + jj) * GN + gc] = f2bf(v);
      }
    }
  }
}

__global__ __launch_bounds__(256, 2) void gemm_qkv_kernel(
    const uint16_t* __restrict__ X,
    const uint16_t* __restrict__ Wq, const uint16_t* __restrict__ Wk, const uint16_t* __restrict__ Wv,
    const float* __restrict__ bq, const float* __restrict__ bk, const float* __restrict__ bv,
    uint16_t* __restrict__ qo, uint16_t* __restrict__ ko, uint16_t* __restrict__ vo) {
  const uint16_t* W; const float* bias; uint16_t* out;
  if (blockIdx.z == 0)      { W = Wq; bias = bq; out = qo; }
  else if (blockIdx.z == 1) { W = Wk; bias = bk; out = ko; }
  else                      { W = Wv; bias = bv; out = vo; }
  gemm_body<0>(X, W, bias, out);
}

__global__ __launch_bounds__(256, 2) void gemm_out_kernel(
    const uint16_t* __restrict__ ctx, const uint16_t* __restrict__ Wo,
    const float* __restrict__ bo, float* __restrict__ out) {
  gemm_body<1>(ctx, Wo, bo, out);
}

// ---------------- flash attention ----------------
// block = (q-tile 64, head, batch); 4 waves x 16 q-rows each.
// ST = K @ Q^T (swapped) so lane holds kv-values of one q-col; P staged per-wave; V transposed in LDS.
__global__ __launch_bounds__(256, 2) void attn_kernel(
    const uint16_t* __restrict__ q, const uint16_t* __restrict__ k,
    const uint16_t* __restrict__ v, const float* __restrict__ mask,
    uint16_t* __restrict__ ctx) {
  __shared__ __align__(16) char smQ[64 * 256];
  __shared__ __align__(16) char smK[64 * 256];
  __shared__ __align__(16) char smVT[128 * 128];  // [d][kv] bf16
  __shared__ __align__(16) char smP[64 * 128];    // [q][kv] bf16 (per-wave 16-row slices)
  __shared__ float smMask[64];
  __shared__ float smScale[64];

  const int tid = threadIdx.x, lane = tid & 63, wid = tid >> 6;
  const int c = lane & 15, g = lane >> 4;
  const int b = blockIdx.z, h = blockIdx.y, q0 = blockIdx.x * 64;
  const float scale = 0.022097086912079608f;  // 1/sqrt(2048)

  // stage Q once (16KB)
#pragma unroll
  for (int i = 0; i < 4; ++i) {
    uint32_t o = wid * 4096 + i * 1024 + lane * 16;
    uint32_t r = o >> 8;
    uint32_t cb = swz256(o) & 255;
    gload_lds16((const char*)q + ((size_t)(b * SEQ + q0 + r) * HDIM + h * DHEAD) * 2 + cb,
                smQ + wid * 4096 + i * 1024);
  }

  float mreg = -1e30f, lreg = 0.f;
  f32x4 oacc[8] = {};

  for (int t = 0; t < 16; ++t) {
    const int kv0 = t * 64;
    __syncthreads();  // prior tile's reads done before overwrite
    // stage K tile (swizzled via pre-swizzled source)
#pragma unroll
    for (int i = 0; i < 4; ++i) {
      uint32_t o = wid * 4096 + i * 1024 + lane * 16;
      uint32_t r = o >> 8;
      uint32_t cb = swz256(o) & 255;
      gload_lds16((const char*)k + ((size_t)(b * SEQ + kv0 + r) * HDIM + h * DHEAD) * 2 + cb,
                  smK + wid * 4096 + i * 1024);
    }
    if (tid < 64) smMask[tid] = mask[b * SEQ + kv0 + tid];
    {  // V transpose: thread covers kv=tid>>2, d = (tid&3)*32 .. +31
      const int kvr = tid >> 2, dblk = tid & 3;
      const uint16_t* src = v + (size_t)(b * SEQ + kv0 + kvr) * HDIM + h * DHEAD + dblk * 32;
      uint16_t tmp[32];
      *(int4*)(tmp)      = *(const int4*)(src);
      *(int4*)(tmp + 8)  = *(const int4*)(src + 8);
      *(int4*)(tmp + 16) = *(const int4*)(src + 16);
      *(int4*)(tmp + 24) = *(const int4*)(src + 24);
#pragma unroll
      for (int e = 0; e < 32; ++e) {
        int d = dblk * 32 + e;
        *(uint16_t*)(smVT + swz128((uint32_t)(d * 128 + kvr * 2))) = tmp[e];
      }
    }
    __syncthreads();

    // ST = K @ Q^T : D[kv][q], per wave N=16 q-cols
    f32x4 st[4] = {};
#pragma unroll
    for (int ks = 0; ks < 4; ++ks) {
      short8 qf = *(const short8*)(smQ + swz256((uint32_t)((wid * 16 + c) * 256 + ks * 64 + g * 16)));
#pragma unroll
      for (int mi = 0; mi < 4; ++mi) {
        short8 kf = *(const short8*)(smK + swz256((uint32_t)((mi * 16 + c) * 256 + ks * 64 + g * 16)));
        st[mi] = __builtin_amdgcn_mfma_f32_16x16x32_bf16(kf, qf, st[mi], 0, 0, 0);
      }
    }
    // scale + mask + row stats (lane holds 16 kv values for q-col = wid*16+c)
    float sv[4][4];
    float pmax = -1e30f;
#pragma unroll
    for (int mi = 0; mi < 4; ++mi) {
      float4 mb = *(const float4*)(smMask + mi * 16 + g * 4);
      float mbv[4] = {mb.x, mb.y, mb.z, mb.w};
#pragma unroll
      for (int jj = 0; jj < 4; ++jj) {
        float s = st[mi][jj] * scale;
        if (mbv[jj] == 0.f) s = -1e9f;
        sv[mi][jj] = s;
        pmax = fmaxf(pmax, s);
      }
    }
    pmax = fmaxf(pmax, __shfl_xor(pmax, 16, 64));
    pmax = fmaxf(pmax, __shfl_xor(pmax, 32, 64));
    float mnew = fmaxf(mreg, pmax);
    float fac = __expf(mreg - mnew);
    float rsum = 0.f;
    uint32_t pw[4][2];
#pragma unroll
    for (int mi = 0; mi < 4; ++mi) {
      float p0 = __expf(sv[mi][0] - mnew);
      float p1 = __expf(sv[mi][1] - mnew);
      float p2 = __expf(sv[mi][2] - mnew);
      float p3 = __expf(sv[mi][3] - mnew);
      rsum += (p0 + p1) + (p2 + p3);
      pw[mi][0] = f2bf(p0) | ((uint32_t)f2bf(p1) << 16);
      pw[mi][1] = f2bf(p2) | ((uint32_t)f2bf(p3) << 16);
    }
    rsum += __shfl_xor(rsum, 16, 64);
    rsum += __shfl_xor(rsum, 32, 64);
    lreg = lreg * fac + rsum;
    mreg = mnew;
    // write P (bf16) into per-wave LDS slice
#pragma unroll
    for (int mi = 0; mi < 4; ++mi) {
      uint32_t addr = swz128((uint32_t)((wid * 16 + c) * 128 + (mi * 16 + g * 4) * 2));
      uint2 wv; wv.x = pw[mi][0]; wv.y = pw[mi][1];
      *(uint2*)(smP + addr) = wv;
    }
    if (g == 0) smScale[wid * 16 + c] = fac;
    __syncthreads();  // P + scale visible (also keeps waves in lockstep)

    // O rescale then O += P @ V
    float4 fv = *(const float4*)(smScale + wid * 16 + g * 4);
    float fvv[4] = {fv.x, fv.y, fv.z, fv.w};
#pragma unroll
    for (int nj = 0; nj < 8; ++nj)
#pragma unroll
      for (int jj = 0; jj < 4; ++jj) oacc[nj][jj] *= fvv[jj];
#pragma unroll
    for (int ks = 0; ks < 2; ++ks) {
      short8 pf = *(const short8*)(smP + swz128((uint32_t)((wid * 16 + c) * 128 + ks * 64 + g * 16)));
#pragma unroll
      for (int nj = 0; nj < 8; ++nj) {
        short8 vf = *(const short8*)(smVT + swz128((uint32_t)((nj * 16 + c) * 128 + ks * 64 + g * 16)));
        oacc[nj] = __builtin_amdgcn_mfma_f32_16x16x32_bf16(pf, vf, oacc[nj], 0, 0, 0);
      }
    }
  }

  __syncthreads();
  if (g == 0) smScale[wid * 16 + c] = lreg;
  __syncthreads();
  float4 lv = *(const float4*)(smScale + wid * 16 + g * 4);
  float inv[4] = {1.f / lv.x, 1.f / lv.y, 1.f / lv.z, 1.f / lv.w};
#pragma unroll
  for (int nj = 0; nj < 8; ++nj) {
#pragma unroll
    for (int jj = 0; jj < 4; ++jj) {
      int qrow = q0 + wid * 16 + g * 4 + jj;
      int dcol = h * DHEAD + nj * 16 + c;
      ctx[(size_t)(b * SEQ + qrow) * HDIM + dcol] = f2bf(oacc[nj][jj] * inv[jj]);
    }
  }
}

// ---------------- launch ----------------
extern "C" void kernel_launch(void* const* d_in, const int* in_sizes, int n_in,
                              void* d_out, int out_size, void* d_ws, size_t ws_size,
                              hipStream_t stream) {
  const float* hs   = (const float*)d_in[0];
  const float* fcos = (const float*)d_in[1];
  const float* fsin = (const float*)d_in[2];
  const float* mask = (const float*)d_in[3];
  const float* Wq = (const float*)d_in[4];  const float* bq = (const float*)d_in[5];
  const float* Wk = (const float*)d_in[6];  const float* bk = (const float*)d_in[7];
  const float* Wv = (const float*)d_in[8];  const float* bv = (const float*)d_in[9];
  const float* Wo = (const float*)d_in[10]; const float* bo = (const float*)d_in[11];
  float* out = (float*)d_out;

  char* ws = (char*)d_ws;
  const size_t XB = (size_t)GM * HDIM * 2;    // 16,777,216
  const size_t WB = (size_t)HDIM * HDIM * 2;  //  8,388,608
  uint16_t* Xbf = (uint16_t*)(ws);            // reused as ctx after QKV
  uint16_t* Wqb = (uint16_t*)(ws + XB);
  uint16_t* Wkb = (uint16_t*)(ws + XB + WB);
  uint16_t* Wvb = (uint16_t*)(ws + XB + 2 * WB);
  uint16_t* Wob = (uint16_t*)(ws + XB + 3 * WB);
  uint16_t* qb  = (uint16_t*)(ws + XB + 4 * WB);
  uint16_t* kb  = (uint16_t*)(ws + XB + 4 * WB + XB);
  uint16_t* vb  = (uint16_t*)(ws + XB + 4 * WB + 2 * XB);

  cvt_kernel<<<4096, 256, 0, stream>>>(hs, Xbf, (GM * HDIM) / 8);
  cvt_kernel<<<2048, 256, 0, stream>>>(Wq, Wqb, (HDIM * HDIM) / 8);
  cvt_kernel<<<2048, 256, 0, stream>>>(Wk, Wkb, (HDIM * HDIM) / 8);
  cvt_kernel<<<2048, 256, 0, stream>>>(Wv, Wvb, (HDIM * HDIM) / 8);
  cvt_kernel<<<2048, 256, 0, stream>>>(Wo, Wob, (HDIM * HDIM) / 8);

  gemm_qkv_kernel<<<dim3(GM / 128, GN / 128, 3), 256, 0, stream>>>(
      Xbf, Wqb, Wkb, Wvb, bq, bk, bv, qb, kb, vb);

  rope_kernel<<<dim3((GM * HDIM) / 8 / 256, 2, 1), 256, 0, stream>>>(qb, kb, fcos, fsin);

  attn_kernel<<<dim3(SEQ / 64, NHEAD, BATCH), 256, 0, stream>>>(qb, kb, vb, mask, Xbf);

  gemm_out_kernel<<<dim3(GM / 128, GN / 128, 1), 256, 0, stream>>>(Xbf, Wob, bo, out);
}